// Round 2
// baseline (68.628 us; speedup 1.0000x reference)
//
#include <hip/hip_runtime.h>

// HashEmbedding: out[b,:] = sum_h table[hash(x[b,h]), :]
//   hash(id) = (u32(id) * 2654435761) % 1_000_000
// x: [4096, 200] int32, table: [1_000_000, 128] f32, out: [4096, 128] f32
//
// L3-blocked gather: 33.5% of the 819,200 row-gathers are repeats
// (544.6K unique rows of 1M). Single random pass evicts repeats before
// reuse (286 MB unique footprint > 256 MB L3). Split gathers into 4
// bucket-range passes (~70 MB unique footprint each << L3); all 4096
// waves are co-resident so the grid sweeps each quartile in lockstep and
// repeats hit Infinity Cache. Indices are partitioned into per-quartile
// LDS lists up front so each pass is a dense unrolled gather loop.

#define BUCKET        1000000u
#define EMBED_DIM     128
#define HIST          200
#define ROWS_PER_BLK  4          // 4 waves x 64 lanes = 256 threads
#define NPASS         4
#define QRANGE        (BUCKET / NPASS)   // 250000

__global__ __launch_bounds__(256, 4)
void hashemb_kernel(const int* __restrict__ x,
                    const float* __restrict__ table,
                    float* __restrict__ out,
                    int batch) {
    // Per-row, per-quartile compacted index lists. HIST capacity per list
    // (no overflow possible). 4*4*200*4B = 12.8 KB.
    __shared__ int lists[ROWS_PER_BLK][NPASS][HIST];
    __shared__ int cnt[ROWS_PER_BLK][NPASS];

    const int row0 = blockIdx.x * ROWS_PER_BLK;

    if (threadIdx.x < ROWS_PER_BLK * NPASS)
        (&cnt[0][0])[threadIdx.x] = 0;
    __syncthreads();

    // Cooperative hash + partition of this block's 800 ids (coalesced).
    const int* xblk = x + (size_t)row0 * HIST;
    const int nids = min(batch - row0, ROWS_PER_BLK) * HIST;
    for (int i = threadIdx.x; i < nids; i += 256) {
        const unsigned int id = (unsigned int)xblk[i];
        const int idx = (int)((id * 2654435761u) % BUCKET);  // magic-mul mod
        const int r = i / HIST;                               // row in block
        const int q = idx / QRANGE;                           // table quartile
        const int pos = atomicAdd(&cnt[r][q], 1);
        lists[r][q][pos] = idx;
    }
    __syncthreads();

    const int wave = threadIdx.x >> 6;   // row within block
    const int lane = threadIdx.x & 63;   // lane*2 -> float2 slice of 128 dims
    const int row  = row0 + wave;
    if (row >= batch) return;

    float accx = 0.f, accy = 0.f;
    for (int p = 0; p < NPASS; ++p) {
        const int n = cnt[wave][p];
        const int* __restrict__ lst = &lists[wave][p][0];
        #pragma unroll 8
        for (int h = 0; h < n; ++h) {
            const float2 v = *reinterpret_cast<const float2*>(
                table + (size_t)lst[h] * EMBED_DIM + lane * 2);
            accx += v.x;
            accy += v.y;
        }
    }

    float2 r2;
    r2.x = accx;
    r2.y = accy;
    *reinterpret_cast<float2*>(out + (size_t)row * EMBED_DIM + lane * 2) = r2;
}

extern "C" void kernel_launch(void* const* d_in, const int* in_sizes, int n_in,
                              void* d_out, int out_size, void* d_ws, size_t ws_size,
                              hipStream_t stream) {
    const int*   x     = (const int*)d_in[0];
    const float* table = (const float*)d_in[1];
    float*       out   = (float*)d_out;

    const int batch = in_sizes[0] / HIST;                         // 4096
    const int grid  = (batch + ROWS_PER_BLK - 1) / ROWS_PER_BLK;  // 1024

    hashemb_kernel<<<grid, 256, 0, stream>>>(x, table, out, batch);
}

// Round 3
// 67.401 us; speedup vs baseline: 1.0182x; 1.0182x over previous
//
#include <hip/hip_runtime.h>

// HashEmbedding: out[b,:] = sum_h table[hash(x[b,h]), :]
//   hash(id) = (u32(id) * 2654435761) % 1_000_000
// x: [4096, 200] int32, table: [1_000_000, 128] f32, out: [4096, 128] f32
//
// Memory-bound random gather: 819,200 rows x 512 B = 419 MB delivered.
// Measured 6.4 TB/s delivery == streaming-copy ceiling (m13: 6.29 TB/s);
// L3-blocked multi-pass variant (round 2) showed 0 gain -> the L2-miss
// delivery path is the binding constraint, not HBM fetch, so cached
// repeats don't help. This is the round-1 structure: one wave per batch
// row (lane -> float2 slice), indices pre-hashed into LDS so the gather
// loop unrolls with no dependent index load (8+ gathers in flight/wave).

#define BUCKET        1000000u
#define EMBED_DIM     128
#define HIST          200
#define ROWS_PER_BLK  4          // 4 waves x 64 lanes = 256 threads

__global__ __launch_bounds__(256, 4)
void hashemb_kernel(const int* __restrict__ x,
                    const float* __restrict__ table,
                    float* __restrict__ out,
                    int batch) {
    __shared__ int sidx[ROWS_PER_BLK * HIST];

    const int row0 = blockIdx.x * ROWS_PER_BLK;

    // Cooperative load + hash of this block's 800 ids (coalesced, once).
    const int* xblk = x + (size_t)row0 * HIST;
    for (int i = threadIdx.x; i < ROWS_PER_BLK * HIST; i += 256) {
        unsigned int id = (unsigned int)xblk[i];
        sidx[i] = (int)((id * 2654435761u) % BUCKET);   // const mod -> magic mul
    }
    __syncthreads();

    const int wave = threadIdx.x >> 6;   // row within block
    const int lane = threadIdx.x & 63;   // lane*2 -> float2 slice of 128 dims
    const int row  = row0 + wave;
    if (row >= batch) return;

    const int* __restrict__ my = &sidx[wave * HIST];

    float accx = 0.f, accy = 0.f;
    #pragma unroll 8
    for (int h = 0; h < HIST; ++h) {
        const float2 v = *reinterpret_cast<const float2*>(
            table + (size_t)my[h] * EMBED_DIM + lane * 2);
        accx += v.x;
        accy += v.y;
    }

    float2 r;
    r.x = accx;
    r.y = accy;
    *reinterpret_cast<float2*>(out + (size_t)row * EMBED_DIM + lane * 2) = r;
}

extern "C" void kernel_launch(void* const* d_in, const int* in_sizes, int n_in,
                              void* d_out, int out_size, void* d_ws, size_t ws_size,
                              hipStream_t stream) {
    const int*   x     = (const int*)d_in[0];
    const float* table = (const float*)d_in[1];
    float*       out   = (float*)d_out;

    const int batch = in_sizes[0] / HIST;                         // 4096
    const int grid  = (batch + ROWS_PER_BLK - 1) / ROWS_PER_BLK;  // 1024

    hashemb_kernel<<<grid, 256, 0, stream>>>(x, table, out, batch);
}